// Round 8
// baseline (621.476 us; speedup 1.0000x reference)
//
#include <hip/hip_runtime.h>

#define N_RID  100000
#define N_CELL 400000
#define NCOLS  4
#define NE     100000
#define D      64
#define TOTE   (NCOLS * NE)          // 400000 edges per direction
#define TILE   64                    // rows per block

typedef __attribute__((ext_vector_type(8))) short bf16x8;
typedef __attribute__((ext_vector_type(4))) float f32x4;

__device__ inline unsigned short f2bf(float f) {
    unsigned int u = __float_as_uint(f);
    return (unsigned short)((u + 0x7FFF + ((u >> 16) & 1)) >> 16);
}
// packed 2xf32 -> 2xbf16 (low16 = a, high16 = b)
__device__ inline unsigned int cvtpk(float a, float b) {
    unsigned int r;
    asm("v_cvt_pk_bf16_f32 %0, %1, %2" : "=v"(r) : "v"(a), "v"(b));
    return r;
}
// byte offset within a [16 rows][128B] bf16 tile, XOR-swizzled
__device__ inline int swz(int row, int kbyte) {
    return row * 128 + (kbyte ^ ((row & 7) << 4));
}

// ================================================================ CSR build
__global__ void hist_kernel(const int* __restrict__ dst, int* __restrict__ cnt,
                            int ndst) {
    int t = blockIdx.x * 256 + threadIdx.x;
    if (t >= TOTE) return;
    int c = t / NE;
    atomicAdd(&cnt[c * ndst + dst[t]], 1);
}

__global__ void scan1(const int* __restrict__ in, int* __restrict__ out,
                      int* __restrict__ csum, int n) {
    __shared__ int lds[256];
    int base = blockIdx.x * 1024 + threadIdx.x * 4;
    int v0 = 0, v1 = 0, v2 = 0, v3 = 0;
    if (base + 0 < n) v0 = in[base + 0];
    if (base + 1 < n) v1 = in[base + 1];
    if (base + 2 < n) v2 = in[base + 2];
    if (base + 3 < n) v3 = in[base + 3];
    int tsum = v0 + v1 + v2 + v3;
    lds[threadIdx.x] = tsum;
    __syncthreads();
    for (int off = 1; off < 256; off <<= 1) {
        int x = (threadIdx.x >= off) ? lds[threadIdx.x - off] : 0;
        __syncthreads();
        lds[threadIdx.x] += x;
        __syncthreads();
    }
    int excl = lds[threadIdx.x] - tsum;
    if (base + 0 < n) out[base + 0] = excl;
    if (base + 1 < n) out[base + 1] = excl + v0;
    if (base + 2 < n) out[base + 2] = excl + v0 + v1;
    if (base + 3 < n) out[base + 3] = excl + v0 + v1 + v2;
    if (threadIdx.x == 255) csum[blockIdx.x] = lds[255];
}

__global__ void scan2(int* __restrict__ a, int m) {
    __shared__ int lds[256];
    int per = (m + 255) >> 8;
    int st = threadIdx.x * per;
    int s = 0;
    for (int i = 0; i < per; ++i) if (st + i < m) s += a[st + i];
    lds[threadIdx.x] = s;
    __syncthreads();
    for (int off = 1; off < 256; off <<= 1) {
        int x = (threadIdx.x >= off) ? lds[threadIdx.x - off] : 0;
        __syncthreads();
        lds[threadIdx.x] += x;
        __syncthreads();
    }
    int run = lds[threadIdx.x] - s;
    for (int i = 0; i < per; ++i) if (st + i < m) { int v = a[st + i]; a[st + i] = run; run += v; }
}

__global__ void scan3(int* __restrict__ out, const int* __restrict__ csum, int n) {
    int i = blockIdx.x * 256 + threadIdx.x;
    if (i < n) out[i] += csum[i >> 10];
}

__global__ void set_sentinels(int* __restrict__ pF, int* __restrict__ pR) {
    if (threadIdx.x == 0) {
        pF[NCOLS * N_CELL] = TOTE;
        pR[NCOLS * N_RID]  = TOTE;
    }
}

__global__ void fill_kernel(const int* __restrict__ dst, const int* __restrict__ src,
                            const int* __restrict__ ptr, int* __restrict__ cnt,
                            int* __restrict__ col, int ndst) {
    int t = blockIdx.x * 256 + threadIdx.x;
    if (t >= TOTE) return;
    int c = t / NE;
    int bin = c * ndst + dst[t];
    int old = atomicSub(&cnt[bin], 1);
    col[ptr[bin] + old - 1] = src[t];
}

// ---------------- W prep: Wt[c][j][k] = bf16(W[c][k][j]) for 4 weight sets
__global__ void prep_w(const float* __restrict__ Wa, const float* __restrict__ Wb,
                       const float* __restrict__ Wc, const float* __restrict__ Wd,
                       unsigned short* __restrict__ Ta, unsigned short* __restrict__ Tb,
                       unsigned short* __restrict__ Tc, unsigned short* __restrict__ Td) {
    int t = blockIdx.x * 256 + threadIdx.x;
    if (t >= NCOLS * D * D) return;
    int c = t >> 12, jk = t & 4095, j = jk >> 6, k = jk & 63;
    int s = (c * D + k) * D + j;
    Ta[t] = f2bf(Wa[s]);
    Tb[t] = f2bf(Wb[s]);
    Tc[t] = f2bf(Wc[s]);
    Td[t] = f2bf(Wd[s]);
}

// ============================ unified SAGE layer kernel ======================
// Wave w owns rows [w*16, w*16+16). The gather runs ONE step-loop that issues
// an edge-row load from EVERY active (relation, row-pair) bin per step — 8
// independent loads in flight instead of a serial per-bin walk. Relations then
// convert+MFMA sequentially, pre-scaled by 1/(deg+1), into one accumulator.
__global__ void __launch_bounds__(256, 4) sage_fused(
        const float* __restrict__ h_dst, const float* __restrict__ h_src,
        const int* __restrict__ ptr, const int* __restrict__ col,
        const unsigned short* __restrict__ Wt, const float* __restrict__ bias,
        const float* __restrict__ mu_d, const float* __restrict__ mu_s,
        float* __restrict__ out, float* __restrict__ csum, int n_dst) {
    __shared__ int pl[NCOLS][TILE + 1];              // ~1 KB
    __shared__ unsigned short aHi[4][16 * D];        // 8 KB (2 KB per wave)
    __shared__ unsigned short aLo[4][16 * D];        // 8 KB

    const int tid = threadIdx.x, w = tid >> 6, l = tid & 63;
    const int g = l >> 3, q = l & 7;                 // 8-lane group, lane-in-group
    const int row0 = blockIdx.x * TILE;

    // coalesced ptr prefetch (clamped; sentinel entry valid)
    for (int i = tid; i < NCOLS * (TILE + 1); i += 256) {
        int cc = i / (TILE + 1), r = i % (TILE + 1);
        pl[cc][r] = ptr[(size_t)cc * n_dst + min(row0 + r, n_dst)];
    }

    // self term (h_dst - mu_d) for the wave's 2 owned rows, fanned to 4 relations
    float4 t0[NCOLS][2], t1[NCOLS][2];
#pragma unroll
    for (int i = 0; i < 2; ++i) {
        int re = min(row0 + w * 16 + i * 8 + g, n_dst - 1);
        const float4* hp = (const float4*)(h_dst + (size_t)re * D);
        float4 v0 = hp[2 * q], v1 = hp[2 * q + 1];
        if (mu_d) {
            float4 m0 = ((const float4*)mu_d)[2 * q], m1 = ((const float4*)mu_d)[2 * q + 1];
            v0.x -= m0.x; v0.y -= m0.y; v0.z -= m0.z; v0.w -= m0.w;
            v1.x -= m1.x; v1.y -= m1.y; v1.z -= m1.z; v1.w -= m1.w;
        }
#pragma unroll
        for (int c = 0; c < NCOLS; ++c) { t0[c][i] = v0; t1[c][i] = v1; }
    }
    float4 ms0 = {0, 0, 0, 0}, ms1 = {0, 0, 0, 0};
    if (mu_s) { ms0 = ((const float4*)mu_s)[2 * q]; ms1 = ((const float4*)mu_s)[2 * q + 1]; }
    __syncthreads();   // pl ready; only barrier

    // cursors + first-col prefetch for all 8 bins
    int rem[NCOLS][2], eN[NCOLS][2], vv[NCOLS][2];
#pragma unroll
    for (int c = 0; c < NCOLS; ++c)
#pragma unroll
        for (int i = 0; i < 2; ++i) {
            int r = w * 16 + i * 8 + g;
            int p0 = pl[c][r];
            int d = pl[c][r + 1] - p0;
            rem[c][i] = d;
            eN[c][i] = p0 + 1;
            vv[c][i] = (d > 0) ? col[p0] : 0;
        }

    // interleaved gather: one edge from every active bin per step
    for (;;) {
        int live = rem[0][0] | rem[0][1] | rem[1][0] | rem[1][1]
                 | rem[2][0] | rem[2][1] | rem[3][0] | rem[3][1];
        if (!live) break;
#pragma unroll
        for (int c = 0; c < NCOLS; ++c)
#pragma unroll
            for (int i = 0; i < 2; ++i) {
                if (rem[c][i] > 0) {
                    const float4* sp = (const float4*)(h_src + (size_t)vv[c][i] * D);
                    float4 u0 = sp[2 * q], u1 = sp[2 * q + 1];
                    if (rem[c][i] > 1) vv[c][i] = col[eN[c][i]];
                    eN[c][i]++; rem[c][i]--;
                    t0[c][i].x += u0.x; t0[c][i].y += u0.y;
                    t0[c][i].z += u0.z; t0[c][i].w += u0.w;
                    t1[c][i].x += u1.x; t1[c][i].y += u1.y;
                    t1[c][i].z += u1.z; t1[c][i].w += u1.w;
                }
            }
    }

    // per relation: scale -> packed bf16 hi/lo -> LDS -> MFMA accumulate
    f32x4 macc[4] = {};
#pragma unroll
    for (int c = 0; c < NCOLS; ++c) {
#pragma unroll
        for (int i = 0; i < 2; ++i) {
            int rloc = i * 8 + g;
            int row = w * 16 + rloc;
            float dg = (float)(pl[c][row + 1] - pl[c][row]);
            float scv = 1.0f / (dg + 1.0f);
            float4 a = t0[c][i], b = t1[c][i];
            a.x = (a.x - dg * ms0.x) * scv; a.y = (a.y - dg * ms0.y) * scv;
            a.z = (a.z - dg * ms0.z) * scv; a.w = (a.w - dg * ms0.w) * scv;
            b.x = (b.x - dg * ms1.x) * scv; b.y = (b.y - dg * ms1.y) * scv;
            b.z = (b.z - dg * ms1.z) * scv; b.w = (b.w - dg * ms1.w) * scv;
            unsigned int h01 = cvtpk(a.x, a.y), h23 = cvtpk(a.z, a.w);
            unsigned int h45 = cvtpk(b.x, b.y), h67 = cvtpk(b.z, b.w);
            float r0 = a.x - __uint_as_float(h01 << 16);
            float r1 = a.y - __uint_as_float(h01 & 0xFFFF0000u);
            float r2 = a.z - __uint_as_float(h23 << 16);
            float r3 = a.w - __uint_as_float(h23 & 0xFFFF0000u);
            float r4 = b.x - __uint_as_float(h45 << 16);
            float r5 = b.y - __uint_as_float(h45 & 0xFFFF0000u);
            float r6 = b.z - __uint_as_float(h67 << 16);
            float r7 = b.w - __uint_as_float(h67 & 0xFFFF0000u);
            unsigned int l01 = cvtpk(r0, r1), l23 = cvtpk(r2, r3);
            unsigned int l45 = cvtpk(r4, r5), l67 = cvtpk(r6, r7);
            int off = swz(rloc, q * 16);
            *(unsigned long long*)((char*)aHi[w] + off) =
                (unsigned long long)h01 | ((unsigned long long)h23 << 32);
            *(unsigned long long*)((char*)aHi[w] + off + 8) =
                (unsigned long long)h45 | ((unsigned long long)h67 << 32);
            *(unsigned long long*)((char*)aLo[w] + off) =
                (unsigned long long)l01 | ((unsigned long long)l23 << 32);
            *(unsigned long long*)((char*)aLo[w] + off + 8) =
                (unsigned long long)l45 | ((unsigned long long)l67 << 32);
        }
        // wave-local LDS RAW (compiler inserts lgkmcnt)
        bf16x8 ah[2], al[2];
#pragma unroll
        for (int kh = 0; kh < 2; ++kh) {
            int off = swz(l & 15, kh * 64 + (l >> 4) * 16);
            ah[kh] = *(const bf16x8*)((const char*)aHi[w] + off);
            al[kh] = *(const bf16x8*)((const char*)aLo[w] + off);
        }
        // JIT W fragments (L1/L2-resident 32 KB set) + MFMA accumulate
#pragma unroll
        for (int nt = 0; nt < 4; ++nt) {
            const unsigned short* wb = Wt + ((c * D + nt * 16 + (l & 15)) * D + (l >> 4) * 8);
            bf16x8 w0 = *(const bf16x8*)(wb);
            bf16x8 w1 = *(const bf16x8*)(wb + 32);
            macc[nt] = __builtin_amdgcn_mfma_f32_16x16x32_bf16(ah[0], w0, macc[nt], 0, 0, 0);
            macc[nt] = __builtin_amdgcn_mfma_f32_16x16x32_bf16(ah[1], w1, macc[nt], 0, 0, 0);
            macc[nt] = __builtin_amdgcn_mfma_f32_16x16x32_bf16(al[0], w0, macc[nt], 0, 0, 0);
            macc[nt] = __builtin_amdgcn_mfma_f32_16x16x32_bf16(al[1], w1, macc[nt], 0, 0, 0);
        }
    }

    // epilogue: wave-local store + fused column-sum
    const int j0 = l & 15;
    float bbv[4];
#pragma unroll
    for (int nt = 0; nt < 4; ++nt)
        bbv[nt] = 0.25f * (bias[nt * 16 + j0] + bias[64 + nt * 16 + j0] +
                           bias[128 + nt * 16 + j0] + bias[192 + nt * 16 + j0]);
    float cs[4] = {0.f, 0.f, 0.f, 0.f};
#pragma unroll
    for (int nt = 0; nt < 4; ++nt)
#pragma unroll
        for (int qq = 0; qq < 4; ++qq) {
            int grow = row0 + w * 16 + (l >> 4) * 4 + qq;
            if (grow < n_dst) {
                float v = 0.25f * macc[nt][qq] + bbv[nt];
                out[(size_t)grow * D + nt * 16 + j0] = v;
                cs[nt] += v;
            }
        }
#pragma unroll
    for (int nt = 0; nt < 4; ++nt) {
        float v = cs[nt];
        v += __shfl_xor(v, 16);
        v += __shfl_xor(v, 32);
        if (l < 16) atomicAdd(&csum[(blockIdx.x & 15) * 64 + nt * 16 + l], v);
    }
}

// ----------------- reduce 16 replicas -> mean vector
__global__ void finalize16(const float* __restrict__ rep, float* __restrict__ mu,
                           float inv_n) {
    int j = threadIdx.x;   // 64 threads
    float s = 0.f;
    for (int k = 0; k < 16; ++k) s += rep[k * 64 + j];
    mu[j] = s * inv_n;
}

// ----------------- combine + center + relu (in place on out)
__global__ void final_combine(float* __restrict__ out, const float* __restrict__ rid,
        const float* __restrict__ mu_c, const float* __restrict__ mu_r) {
    int t = blockIdx.x * 256 + threadIdx.x;
    if (t >= N_CELL * D) return;
    int row = t >> 6, j = t & 63;
    float v = (row < N_RID) ? (rid[(size_t)row * D + j] - mu_r[j])
                            : (out[t] - mu_c[j]);
    out[t] = fmaxf(v, 0.0f);
}

extern "C" void kernel_launch(void* const* d_in, const int* in_sizes, int n_in,
                              void* d_out, int out_size, void* d_ws, size_t ws_size,
                              hipStream_t stream) {
    const float* x_rid  = (const float*)d_in[0];
    const float* x_cell = (const float*)d_in[1];
    const int* src_fwd  = (const int*)d_in[2];
    const int* dst_fwd  = (const int*)d_in[3];
    const int* src_rev  = (const int*)d_in[4];
    const int* dst_rev  = (const int*)d_in[5];
    const float* W1f = (const float*)d_in[6];
    const float* b1f = (const float*)d_in[7];
    const float* W1r = (const float*)d_in[8];
    const float* b1r = (const float*)d_in[9];
    const float* W2f = (const float*)d_in[10];
    const float* b2f = (const float*)d_in[11];
    const float* W2r = (const float*)d_in[12];
    const float* b2r = (const float*)d_in[13];
    float* out = (float*)d_out;

    float* ws    = (float*)d_ws;
    float* rid1  = ws;                                   //  6.4M f32
    float* cell1 = rid1  + (size_t)N_RID * D;            // 25.6M
    float* rid2  = cell1 + (size_t)N_CELL * D;           //  6.4M (build overlays)
    float* csums = rid2  + (size_t)N_RID * D;            //  4 x 1024
    float* mus   = csums + 4 * 1024;                     //  4 x 64
    int*   ptrF  = (int*)(mus + 4 * 64);
    int*   colF  = ptrF + (size_t)NCOLS * N_CELL + 1;
    int*   ptrR  = colF + TOTE;
    int*   colR  = ptrR + (size_t)NCOLS * N_RID + 1;
    uintptr_t wp = ((uintptr_t)(colR + TOTE) + 15) & ~(uintptr_t)15;
    unsigned short* Wt1f = (unsigned short*)wp;
    unsigned short* Wt1r = Wt1f + NCOLS * D * D;
    unsigned short* Wt2f = Wt1r + NCOLS * D * D;
    unsigned short* Wt2r = Wt2f + NCOLS * D * D;
    // build-phase overlays inside rid2 region (dead until layer 2)
    int*   cntF  = (int*)rid2;
    int*   cntR  = cntF + (size_t)NCOLS * N_CELL;
    int*   csumF = cntR + (size_t)NCOLS * N_RID;
    int*   csumR = csumF + 2048;

    float* cs_c1 = csums;
    float* cs_r1 = csums + 1024;
    float* cs_o  = csums + 2048;
    float* cs_r2 = csums + 3072;
    float* mu_c1 = mus;
    float* mu_r1 = mus + 64;
    float* mu_o  = mus + 128;
    float* mu_r2 = mus + 192;

    const int NBF = NCOLS * N_CELL;
    const int NBR = NCOLS * N_RID;
    const int g_edges = (TOTE + 255) / 256;

    hipMemsetAsync(cntF, 0, (size_t)NBF * sizeof(int), stream);
    hipMemsetAsync(cntR, 0, (size_t)NBR * sizeof(int), stream);
    hipMemsetAsync(csums, 0, 4 * 1024 * sizeof(float), stream);

    prep_w<<<(NCOLS * D * D + 255) / 256, 256, 0, stream>>>(W1f, W1r, W2f, W2r,
                                                            Wt1f, Wt1r, Wt2f, Wt2r);

    hist_kernel<<<g_edges, 256, 0, stream>>>(dst_fwd, cntF, N_CELL);
    hist_kernel<<<g_edges, 256, 0, stream>>>(dst_rev, cntR, N_RID);
    int nchF = (NBF + 1023) / 1024, nchR = (NBR + 1023) / 1024;
    scan1<<<nchF, 256, 0, stream>>>(cntF, ptrF, csumF, NBF);
    scan2<<<1, 256, 0, stream>>>(csumF, nchF);
    scan3<<<(NBF + 255) / 256, 256, 0, stream>>>(ptrF, csumF, NBF);
    scan1<<<nchR, 256, 0, stream>>>(cntR, ptrR, csumR, NBR);
    scan2<<<1, 256, 0, stream>>>(csumR, nchR);
    scan3<<<(NBR + 255) / 256, 256, 0, stream>>>(ptrR, csumR, NBR);
    set_sentinels<<<1, 64, 0, stream>>>(ptrF, ptrR);
    fill_kernel<<<g_edges, 256, 0, stream>>>(dst_fwd, src_fwd, ptrF, cntF, colF, N_CELL);
    fill_kernel<<<g_edges, 256, 0, stream>>>(dst_rev, src_rev, ptrR, cntR, colR, N_RID);

    const int gC = N_CELL / TILE;                 // 6250
    const int gR = (N_RID + TILE - 1) / TILE;     // 1563

    // ---------------- layer 1 ----------------
    sage_fused<<<gC, 256, 0, stream>>>(x_cell, x_rid, ptrF, colF, Wt1f, b1f,
                                       nullptr, nullptr, cell1, cs_c1, N_CELL);
    sage_fused<<<gR, 256, 0, stream>>>(x_rid, x_cell, ptrR, colR, Wt1r, b1r,
                                       nullptr, nullptr, rid1, cs_r1, N_RID);
    finalize16<<<1, 64, 0, stream>>>(cs_c1, mu_c1, 1.0f / N_CELL);
    finalize16<<<1, 64, 0, stream>>>(cs_r1, mu_r1, 1.0f / N_RID);

    // ---------------- layer 2 ----------------
    sage_fused<<<gC, 256, 0, stream>>>(cell1, rid1, ptrF, colF, Wt2f, b2f,
                                       mu_c1, mu_r1, out, cs_o, N_CELL);
    sage_fused<<<gR, 256, 0, stream>>>(rid1, cell1, ptrR, colR, Wt2r, b2r,
                                       mu_r1, mu_c1, rid2, cs_r2, N_RID);
    finalize16<<<1, 64, 0, stream>>>(cs_o, mu_o, 1.0f / N_CELL);
    finalize16<<<1, 64, 0, stream>>>(cs_r2, mu_r2, 1.0f / N_RID);

    final_combine<<<(N_CELL * D) / 256, 256, 0, stream>>>(out, rid2, mu_o, mu_r2);
}